// Round 4
// baseline (508.065 us; speedup 1.0000x reference)
//
#include <hip/hip_runtime.h>

#define SEQ   2048
#define BATCH 2
#define HID   2048
#define NHEAD 16
#define HDIM  128
#define MTOT  4096
#define KDIM  2048

typedef __attribute__((ext_vector_type(8))) short  bf16x8;
typedef __attribute__((ext_vector_type(4))) float  f32x4;
typedef __attribute__((ext_vector_type(4))) unsigned short u16x4;
typedef __attribute__((ext_vector_type(8))) unsigned short u16x8;

__device__ __forceinline__ unsigned short f2bf(float x) {
  unsigned u = __float_as_uint(x);
  u += 0x7fffu + ((u >> 16) & 1u);
  return (unsigned short)(u >> 16);
}

__device__ __forceinline__ float fexp2(float x) {
  float r;
  asm("v_exp_f32 %0, %1" : "=v"(r) : "v"(x));
  return r;
}

__device__ __forceinline__ void gl_lds16(const void* g, void* l) {
  __builtin_amdgcn_global_load_lds(
      (__attribute__((address_space(1))) void*)g,
      (__attribute__((address_space(3))) void*)l, 16, 0, 0);
}

__device__ __forceinline__ f32x4 mfma16(bf16x8 a, bf16x8 b, f32x4 c) {
  return __builtin_amdgcn_mfma_f32_16x16x32_bf16(a, b, c, 0, 0, 0);
}

// fp32 -> bf16 with K-granule swizzle (rows of length 2048):
// element (r,k) stored at r*2048 + (k ^ (((r>>1)&3)<<3))
__global__ __launch_bounds__(256, 8)
void conv_swz(const float* __restrict__ src, unsigned short* __restrict__ dst) {
  int i = blockIdx.x * 256 + threadIdx.x;
  int base = i << 2;
  int r = base >> 11, k = base & 2047;
  f32x4 v = *(const f32x4*)(src + base);
  int kp = k ^ (((r >> 1) & 3) << 3);
  u16x4 o;
  o[0] = f2bf(v[0]); o[1] = f2bf(v[1]); o[2] = f2bf(v[2]); o[3] = f2bf(v[3]);
  *(u16x4*)(dst + (size_t)r * 2048 + kp) = o;
}

__global__ __launch_bounds__(256, 8)
void rope_cache_k(float* __restrict__ cosT, float* __restrict__ sinT) {
  int idx = blockIdx.x * 256 + threadIdx.x;   // 2048*64
  int s = idx >> 6, i = idx & 63;
  float inv = powf(1e-4f, (float)i * (1.0f / 64.0f));
  float a = (float)s * inv;
  cosT[idx] = cosf(a);
  sinT[idx] = sinf(a);
}

// ---------------------------------------------------------------------------
// QKV GEMM: 256x384 tile (N-tile = one head's q|k|v triple), BK=32,
// grid EXACTLY 16x16 = 256 blocks (one full dispatch round, no tail).
// 8 waves = 2M x 4N; wave (wr,wc) owns rows [wr*128,+128), col-blocks
// nf = wc + 4*nl (nl=0..5) -> RoPE pairs (d,d+64) = (nl,nl+1) stay in-wave.
// LDS: ring-3 bufs: A[buf][256][32] @ buf*16K (48K), B[buf][384][32]
// @ 49152 + buf*24K (72K) = 120 KiB. Prefetch 2 tiles ahead; vmcnt(5)
// once per tile (5 = loads of one tile: A 2 + B 3). 2 phases/tile
// (M-halves), 24 MFMA per phase.
// ---------------------------------------------------------------------------
__global__ __launch_bounds__(512, 2)
void gemm_qkv(const unsigned short* __restrict__ A,
              const unsigned short* __restrict__ Bt,
              const float* __restrict__ bias,
              unsigned short* __restrict__ Qs,
              unsigned short* __restrict__ Ks,
              unsigned short* __restrict__ Vp,
              const float* __restrict__ cosT,
              const float* __restrict__ sinT)
{
  __shared__ alignas(16) char lds[122880];   // 120 KiB
  const int tid = threadIdx.x;
  const int wid = tid >> 6, lane = tid & 63, g = lane >> 4, c = lane & 15;
  const int wr = wid >> 2, wc = wid & 3;

  // XCD swizzle: XCD x gets swz in [x*32, x*32+32) = 2 n-cols x 16 m-rows
  const int bid = blockIdx.x;
  const int swz = (bid & 7) * 32 + (bid >> 3);
  const int mblk = swz & 15, nblk = swz >> 4;
  const int m0 = mblk << 8;
  const int n0 = nblk * 384;
  const int nh = nblk;

  char* ldsb = (char*)lds;
  const int slotg = (g ^ ((c >> 1) & 3)) << 4;
  const char* ldsAr = ldsb + (wr * 128 + c) * 64 + slotg;
  const char* ldsBr = ldsb + 49152 + (wc * 16 + c) * 64 + slotg;

  const char* gA = (const char*)A  + (size_t)(m0 + (tid >> 2)) * 4096 + (tid & 3) * 16;
  const char* gB = (const char*)Bt + (size_t)(n0 + (tid >> 2)) * 4096 + (tid & 3) * 16;
  char* lA = ldsb + tid * 16;
  char* lB = ldsb + 49152 + tid * 16;

#define STG_A(T, BUF) do { const char* _g = gA + (T) * 64; char* _l = lA + (BUF) * 16384; \
    gl_lds16(_g, _l); gl_lds16(_g + 524288, _l + 8192); } while (0)
#define STG_B(T, BUF) do { const char* _g = gB + (T) * 64; char* _l = lB + (BUF) * 24576; \
    gl_lds16(_g, _l); gl_lds16(_g + 524288, _l + 8192); gl_lds16(_g + 1048576, _l + 16384); } while (0)

  f32x4 acc[8][6];
#pragma unroll
  for (int i = 0; i < 8; ++i)
#pragma unroll
    for (int j = 0; j < 6; ++j) {
      acc[i][j][0] = 0.f; acc[i][j][1] = 0.f; acc[i][j][2] = 0.f; acc[i][j][3] = 0.f;
    }

  bf16x8 a[4], b[6];
  const int NT = KDIM / 32;   // 64

#define PH(T, BUF, MH, STAGE, VMW) do {                                     \
    _Pragma("unroll")                                                       \
    for (int mf = 0; mf < 4; ++mf)                                          \
      a[mf] = *(const bf16x8*)(ldsAr + (BUF) * 16384 + (MH) * 4096 + mf * 1024); \
    if ((MH) == 0) {                                                        \
      _Pragma("unroll")                                                     \
      for (int nl = 0; nl < 6; ++nl)                                        \
        b[nl] = *(const bf16x8*)(ldsBr + (BUF) * 24576 + nl * 4096);        \
    }                                                                       \
    STAGE;                                                                  \
    __builtin_amdgcn_s_barrier();                                           \
    asm volatile("s_waitcnt lgkmcnt(0)" ::: "memory");                      \
    __builtin_amdgcn_s_setprio(1);                                          \
    _Pragma("unroll")                                                       \
    for (int mf = 0; mf < 4; ++mf)                                          \
      _Pragma("unroll")                                                     \
      for (int nl = 0; nl < 6; ++nl)                                        \
        acc[(MH) * 4 + mf][nl] = mfma16(a[mf], b[nl], acc[(MH) * 4 + mf][nl]); \
    __builtin_amdgcn_s_setprio(0);                                          \
    VMW;                                                                    \
    __builtin_amdgcn_s_barrier();                                           \
  } while (0)

#define TILE(T, BUF, BUF2) do {                                             \
    PH(T, BUF, 0, { if ((T) + 2 < NT) STG_A((T) + 2, BUF2); }, ((void)0));  \
    PH(T, BUF, 1, { if ((T) + 2 < NT) STG_B((T) + 2, BUF2); },              \
       { if ((T) + 2 < NT) { asm volatile("s_waitcnt vmcnt(5)" ::: "memory"); } \
         else              { asm volatile("s_waitcnt vmcnt(0)" ::: "memory"); } }); \
  } while (0)

  // Prologue: stage tiles 0,1; drain tile0's 5 loads, keep tile1's in flight.
  STG_A(0, 0); STG_B(0, 0);
  STG_A(1, 1); STG_B(1, 1);
  asm volatile("s_waitcnt vmcnt(5)" ::: "memory");
  __builtin_amdgcn_s_barrier();

  for (int t = 0; t < 63; t += 3) {
    TILE(t, 0, 2);
    TILE(t + 1, 1, 0);
    TILE(t + 2, 2, 1);
  }
  TILE(63, 0, 2);

  // ---- epilogue: bias + RoPE; nl pairs (0,1)=Q, (2,3)=K, (4,5)=V ----
  // log2(e)/sqrt(128) folded into Q for exp2-domain softmax
  const float qsc = 0.08838834764831845f * 1.4426950408889634f;
  const int dl = wc * 16 + c;   // 0..63
#pragma unroll
  for (int ar = 0; ar < 8; ++ar) {
#pragma unroll
    for (int rr = 0; rr < 4; ++rr) {
      int m = m0 + wr * 128 + ar * 16 + g * 4 + rr;
      int s = m >> 1, bb = m & 1;
      size_t plane = (size_t)(bb * NHEAD + nh) * (SEQ * HDIM);
      int swb = (s & 7) << 3;
      float co = cosT[s * 64 + dl], si = sinT[s * 64 + dl];
      {
        float xl = acc[ar][0][rr] + bias[n0 + dl];
        float xr = acc[ar][1][rr] + bias[n0 + 64 + dl];
        Qs[plane + (size_t)s * HDIM + (dl ^ swb)]        = f2bf((co * xl - si * xr) * qsc);
        Qs[plane + (size_t)s * HDIM + ((dl + 64) ^ swb)] = f2bf((si * xl + co * xr) * qsc);
      }
      {
        float xl = acc[ar][2][rr] + bias[n0 + 128 + dl];
        float xr = acc[ar][3][rr] + bias[n0 + 192 + dl];
        Ks[plane + (size_t)s * HDIM + (dl ^ swb)]        = f2bf(co * xl - si * xr);
        Ks[plane + (size_t)s * HDIM + ((dl + 64) ^ swb)] = f2bf(si * xl + co * xr);
      }
      Vp[plane + (size_t)s * HDIM + dl]      = f2bf(acc[ar][4][rr] + bias[n0 + 256 + dl]);
      Vp[plane + (size_t)s * HDIM + dl + 64] = f2bf(acc[ar][5][rr] + bias[n0 + 320 + dl]);
    }
  }
#undef TILE
#undef PH
#undef STG_A
#undef STG_B
}

// ---------------------------------------------------------------------------
// 256x256 8-phase NT GEMM (dense projection only now)
// ---------------------------------------------------------------------------
template<int EPI>
__global__ __launch_bounds__(512, 2)
void gemm8p(const unsigned short* __restrict__ A,
            const unsigned short* __restrict__ Bt,
            const float* __restrict__ bias,
            float* __restrict__ Cout)
{
  __shared__ alignas(16) short lds[65536];   // 128 KiB
  const int tid = threadIdx.x;
  const int wid = tid >> 6, lane = tid & 63, g = lane >> 4, c = lane & 15;
  const int wr = wid >> 1, wc = wid & 1;
  const int m0 = blockIdx.y << 8, n0 = blockIdx.x << 8;

  char* ldsb = (char*)lds;
  const int slotg = (g ^ ((c >> 1) & 3)) << 4;
  const char* ldsAr = ldsb + ((wr * 64 + c) * 64 + slotg);
  const char* ldsBr = ldsb + 65536 + ((wc * 128 + c) * 64 + slotg);

  const char* gA = (const char*)A  + (size_t)(m0 + (tid >> 2)) * 4096 + (tid & 3) * 16;
  const char* gB = (const char*)Bt + (size_t)(n0 + (tid >> 2)) * 4096 + (tid & 3) * 16;
  char* lA = ldsb + tid * 16;
  char* lB = ldsb + 65536 + tid * 16;

#define STG_A(T, KS, BUF) do { int _ko = (T) * 128 + (KS) * 64;            \
    gl_lds16(gA + _ko,          lA + ((BUF) * 2 + (KS)) * 16384);          \
    gl_lds16(gA + _ko + 524288, lA + ((BUF) * 2 + (KS)) * 16384 + 8192); } while (0)
#define STG_B(T, KS, BUF) do { int _ko = (T) * 128 + (KS) * 64;            \
    gl_lds16(gB + _ko,          lB + ((BUF) * 2 + (KS)) * 16384);          \
    gl_lds16(gB + _ko + 524288, lB + ((BUF) * 2 + (KS)) * 16384 + 8192); } while (0)

  f32x4 acc[4][8];
#pragma unroll
  for (int i = 0; i < 4; ++i)
#pragma unroll
    for (int j = 0; j < 8; ++j) {
      acc[i][j][0] = 0.f; acc[i][j][1] = 0.f; acc[i][j][2] = 0.f; acc[i][j][3] = 0.f;
    }

  bf16x8 a[4], b[4];

#define LDA(KS, BUF) do { _Pragma("unroll")                                 \
    for (int mf = 0; mf < 4; ++mf)                                          \
      a[mf] = *(const bf16x8*)(ldsAr + ((BUF) * 2 + (KS)) * 16384 + mf * 1024); } while (0)
#define LDB(KS, NH, BUF) do { _Pragma("unroll")                             \
    for (int nf = 0; nf < 4; ++nf)                                          \
      b[nf] = *(const bf16x8*)(ldsBr + ((BUF) * 2 + (KS)) * 16384 + ((NH) * 4 + nf) * 1024); } while (0)

#define PHASE(NH, KS, BUF, STAGE, VMW) do {                                 \
    if ((NH) == 0) { LDA(KS, BUF); }                                        \
    LDB(KS, NH, BUF);                                                       \
    STAGE;                                                                  \
    __builtin_amdgcn_s_barrier();                                           \
    asm volatile("s_waitcnt lgkmcnt(0)" ::: "memory");                      \
    __builtin_amdgcn_s_setprio(1);                                          \
    _Pragma("unroll")                                                       \
    for (int mf = 0; mf < 4; ++mf)                                          \
      _Pragma("unroll")                                                     \
      for (int nf = 0; nf < 4; ++nf)                                        \
        acc[mf][(NH) * 4 + nf] = mfma16(a[mf], b[nf], acc[mf][(NH) * 4 + nf]); \
    __builtin_amdgcn_s_setprio(0);                                          \
    VMW;                                                                    \
    __builtin_amdgcn_s_barrier();                                           \
  } while (0)

  const int NT = KDIM / 64;   // 32

  STG_A(0, 0, 0); STG_B(0, 0, 0); STG_A(0, 1, 0); STG_B(0, 1, 0);
  STG_A(1, 0, 1); STG_B(1, 0, 1); STG_A(1, 1, 1);
  asm volatile("s_waitcnt vmcnt(6)" ::: "memory");
  __builtin_amdgcn_s_barrier();

#define GROUP(T, BUF) do {                                                  \
    PHASE(0, 0, BUF, { if ((T) + 1 < NT) STG_B((T) + 1, 1, (BUF) ^ 1); }, ((void)0)); \
    PHASE(1, 0, BUF, { if ((T) + 2 < NT) STG_A((T) + 2, 0, (BUF)); },  ((void)0));    \
    PHASE(0, 1, BUF, { if ((T) + 2 < NT) STG_B((T) + 2, 0, (BUF)); },  ((void)0));    \
    PHASE(1, 1, BUF, { if ((T) + 2 < NT) STG_A((T) + 2, 1, (BUF)); },               \
      { if ((T) + 2 < NT) { asm volatile("s_waitcnt vmcnt(6)" ::: "memory"); }      \
        else              { asm volatile("s_waitcnt vmcnt(0)" ::: "memory"); } });  \
  } while (0)

  for (int t = 0; t < NT; t += 2) {
    GROUP(t, 0);
    GROUP(t + 1, 1);
  }

#pragma unroll
  for (int mf = 0; mf < 4; ++mf)
#pragma unroll
    for (int rr = 0; rr < 4; ++rr) {
      int m = m0 + wr * 64 + mf * 16 + g * 4 + rr;
#pragma unroll
      for (int nf = 0; nf < 8; ++nf) {
        int n = n0 + wc * 128 + nf * 16 + c;
        Cout[(size_t)m * HID + n] = acc[mf][nf][rr] + bias[n];
      }
    }
#undef GROUP
#undef PHASE
#undef LDA
#undef LDB
#undef STG_A
#undef STG_B
}

// V [plane][t][d] -> Vt [plane][d][t], t-granule swizzled: (t ^ ((d&7)<<3))
__global__ __launch_bounds__(256, 4)
void transpose_v(const unsigned short* __restrict__ Vp, unsigned short* __restrict__ Vt) {
  __shared__ alignas(16) unsigned short T[64 * 136];
  const int plane = blockIdx.x >> 5;
  const int t0 = (blockIdx.x & 31) << 6;
  const size_t pbase = (size_t)plane * (SEQ * HDIM);
  const int tid = threadIdx.x;
  {
    int t = tid >> 2, d0 = (tid & 3) << 5;
    const unsigned short* src = Vp + pbase + (size_t)(t0 + t) * HDIM + d0;
#pragma unroll
    for (int j = 0; j < 4; ++j) {
      u16x8 v = *(const u16x8*)(src + j * 8);
      *(u16x8*)(&T[t * 136 + d0 + j * 8]) = v;
    }
  }
  __syncthreads();
  {
    int d = tid >> 1, half = tid & 1;
    unsigned short* dstp = Vt + pbase + (size_t)d * SEQ;
    int swb = (d & 7) << 3;
#pragma unroll
    for (int gg = 0; gg < 4; ++gg) {
      u16x8 v;
#pragma unroll
      for (int e = 0; e < 8; ++e)
        v[e] = T[(half * 32 + gg * 8 + e) * 136 + d];
      int tloc = half * 32 + gg * 8;
      *(u16x8*)(dstp + ((t0 + tloc) ^ swb)) = v;
    }
  }
}

// ---------------------------------------------------------------------------
// Flash attention (unchanged from round 3)
// ---------------------------------------------------------------------------
__global__ __launch_bounds__(256, 2)
void attn(const unsigned short* __restrict__ Qs,
          const unsigned short* __restrict__ Ks,
          const unsigned short* __restrict__ Vt,
          unsigned short* __restrict__ ctx)
{
  __shared__ alignas(16) unsigned short Klds[2][64 * 128];
  __shared__ alignas(16) unsigned short Vlds[128 * 64];
  __shared__ alignas(16) unsigned short Plds[128 * 72];
  const int tid = threadIdx.x;
  const int w = tid >> 6, lane = tid & 63, g = lane >> 4, c = lane & 15;
  const int bid = blockIdx.x;
  const int head = bid & 31;
  const int qb = (bid < 256) ? (15 - (bid >> 5)) : ((bid >> 5) - 8);
  const int q0 = qb << 7;
  const size_t plane = (size_t)head * (SEQ * HDIM);
  const unsigned short* Qp = Qs + plane;
  const unsigned short* Kp = Ks + plane;
  const unsigned short* Vp = Vt + plane;

  bf16x8 qf[2][4];
#pragma unroll
  for (int q2 = 0; q2 < 2; ++q2) {
    int s = q0 + w * 32 + q2 * 16 + c;
    int swb = (s & 7) << 3;
#pragma unroll
    for (int kk = 0; kk < 4; ++kk) {
      int d0 = kk * 32 + g * 8;
      qf[q2][kk] = *(const bf16x8*)(Qp + (size_t)s * HDIM + (d0 ^ swb));
    }
  }

  f32x4 accO[2][8];
#pragma unroll
  for (int i = 0; i < 2; ++i)
#pragma unroll
    for (int j = 0; j < 8; ++j) {
      accO[i][j][0] = 0.f; accO[i][j][1] = 0.f; accO[i][j][2] = 0.f; accO[i][j][3] = 0.f;
    }
  float mrun[2] = { -1e30f, -1e30f };
  float lrun[2] = { 0.f, 0.f };

  const char* KgBase = (const char*)Kp + (tid >> 4) * 256 + (tid & 15) * 16;
  const char* VgBase = (const char*)Vp + (size_t)(tid >> 3) * 4096 + (tid & 7) * 16;
  char* VldsW = (char*)Vlds + w * 1024;

  const int ntiles = (q0 >> 6) + 2;
  const int qminw = q0 + w * 32;
  const int qmaxw = qminw + 31;

#pragma unroll
  for (int i = 0; i < 4; ++i)
    gl_lds16(KgBase, (char*)Klds[0] + w * 1024 + i * 4096), KgBase += 4096;
  KgBase -= 16384;

  for (int kt = 0; kt < ntiles; ++kt) {
    const int t0 = kt << 6;
    const bool havenext = (kt + 1 < ntiles);

#pragma unroll
    for (int i = 0; i < 4; ++i)
      gl_lds16(VgBase + t0 * 2 + (size_t)i * 131072, VldsW + i * 4096);
    if (havenext) {
      char* kdst = (char*)Klds[(kt + 1) & 1] + w * 1024;
#pragma unroll
      for (int i = 0; i < 4; ++i)
        gl_lds16(KgBase + (size_t)(t0 + 64) * 256 + i * 4096, kdst + i * 4096);
    }
    if (havenext) asm volatile("s_waitcnt vmcnt(8)" ::: "memory");
    else          asm volatile("s_waitcnt vmcnt(4)" ::: "memory");
    __builtin_amdgcn_s_barrier();

    if (t0 <= qmaxw) {
      const char* Kb = (const char*)Klds[kt & 1];
      f32x4 sacc[4][2];
#pragma unroll
      for (int i = 0; i < 4; ++i)
#pragma unroll
        for (int j = 0; j < 2; ++j) {
          sacc[i][j][0] = 0.f; sacc[i][j][1] = 0.f; sacc[i][j][2] = 0.f; sacc[i][j][3] = 0.f;
        }
      __builtin_amdgcn_s_setprio(1);
#pragma unroll
      for (int kk = 0; kk < 4; ++kk) {
        bf16x8 kf[4];
#pragma unroll
        for (int ta = 0; ta < 4; ++ta) {
          int t = ta * 16 + c;
          int d0 = kk * 32 + g * 8;
          kf[ta] = *(const bf16x8*)(Kb + t * 256 + ((d0 ^ ((t & 7) << 3)) << 1));
        }
#pragma unroll
        for (int ta = 0; ta < 4; ++ta)
#pragma unroll
          for (int q2 = 0; q2 < 2; ++q2)
            sacc[ta][q2] = mfma16(kf[ta], qf[q2][kk], sacc[ta][q2]);
      }
      __builtin_amdgcn_s_setprio(0);

      if (t0 + 63 > qminw) {
#pragma unroll
        for (int ta = 0; ta < 4; ++ta)
#pragma unroll
          for (int q2 = 0; q2 < 2; ++q2)
#pragma unroll
            for (int r = 0; r < 4; ++r) {
              int t = t0 + ta * 16 + g * 4 + r;
              int q = qminw + q2 * 16 + c;
              if (t > q) sacc[ta][q2][r] = -30000.f;
            }
      }

      float corr[2];
      bool resc = false;
#pragma unroll
      for (int q2 = 0; q2 < 2; ++q2) {
        float mx = -30000.f;
#pragma unroll
        for (int ta = 0; ta < 4; ++ta)
          mx = fmaxf(mx, fmaxf(fmaxf(sacc[ta][q2][0], sacc[ta][q2][1]),
                               fmaxf(sacc[ta][q2][2], sacc[ta][q2][3])));
        mx = fmaxf(mx, __shfl_xor(mx, 16));
        mx = fmaxf(mx, __shfl_xor(mx, 32));
        bool rs = mx > mrun[q2] + 8.0f;
        resc |= rs;
        float mnew = rs ? mx : mrun[q2];
        corr[q2] = fexp2(mrun[q2] - mnew);
        mrun[q2] = mnew;
        float ls = 0.f;
#pragma unroll
        for (int ta = 0; ta < 4; ++ta)
#pragma unroll
          for (int r = 0; r < 4; ++r) {
            float e = fexp2(sacc[ta][q2][r] - mnew);
            sacc[ta][q2][r] = e;
            ls += e;
          }
        ls += __shfl_xor(ls, 16);
        ls += __shfl_xor(ls, 32);
        lrun[q2] = lrun[q2] * corr[q2] + ls;
      }

      if (__any(resc)) {
#pragma unroll
        for (int q2 = 0; q2 < 2; ++q2)
#pragma unroll
          for (int r = 0; r < 4; ++r) {
            float cD = __shfl(corr[q2], (lane & 48) | (((lane >> 4) << 2) + r));
#pragma unroll
            for (int fn = 0; fn < 8; ++fn) accO[q2][fn][r] *= cD;
          }
      }

#pragma unroll
      for (int q2 = 0; q2 < 2; ++q2) {
        int prow = w * 32 + q2 * 16 + c;
#pragma unroll
        for (int ta = 0; ta < 4; ++ta) {
          u16x4 pk;
          pk[0] = f2bf(sacc[ta][q2][0]); pk[1] = f2bf(sacc[ta][q2][1]);
          pk[2] = f2bf(sacc[ta][q2][2]); pk[3] = f2bf(sacc[ta][q2][3]);
          *(u16x4*)(&Plds[prow * 72 + ta * 16 + g * 4]) = pk;
        }
      }
    }

    if (havenext) asm volatile("s_waitcnt vmcnt(4)" ::: "memory");
    else          asm volatile("s_waitcnt vmcnt(0)" ::: "memory");
    __builtin_amdgcn_s_barrier();

    if (t0 <= qmaxw) {
      __builtin_amdgcn_s_setprio(1);
#pragma unroll
      for (int kk = 0; kk < 2; ++kk) {
        bf16x8 pa[2];
#pragma unroll
        for (int q2 = 0; q2 < 2; ++q2)
          pa[q2] = *(const bf16x8*)((const char*)Plds + (w * 32 + q2 * 16 + c) * 144 + (kk * 32 + g * 8) * 2);
#pragma unroll
        for (int fn = 0; fn < 8; ++fn) {
          int d = fn * 16 + c;
          int tt = kk * 32 + g * 8;
          bf16x8 vb = *(const bf16x8*)((const char*)Vlds + d * 128 + ((tt ^ ((d & 7) << 3)) << 1));
#pragma unroll
          for (int q2 = 0; q2 < 2; ++q2)
            accO[q2][fn] = mfma16(pa[q2], vb, accO[q2][fn]);
        }
      }
      __builtin_amdgcn_s_setprio(0);
    }
    __builtin_amdgcn_s_barrier();
  }

  const int b = head >> 4, nh = head & 15;
  float linv[2] = { 1.0f / lrun[0], 1.0f / lrun[1] };
#pragma unroll
  for (int q2 = 0; q2 < 2; ++q2)
#pragma unroll
    for (int r = 0; r < 4; ++r) {
      float inv = __shfl(linv[q2], (lane & 48) | (((lane >> 4) << 2) + r));
      int q = q0 + w * 32 + q2 * 16 + g * 4 + r;
      int m = q * 2 + b;
      int swb = ((m >> 1) & 3) << 3;
#pragma unroll
      for (int fn = 0; fn < 8; ++fn) {
        int h = nh * 128 + fn * 16 + c;
        ctx[(size_t)m * HID + (h ^ swb)] = f2bf(accO[q2][fn][r] * inv);
      }
    }
}

extern "C" void kernel_launch(void* const* d_in, const int* in_sizes, int n_in,
                              void* d_out, int out_size, void* d_ws, size_t ws_size,
                              hipStream_t stream) {
  const float* hidden = (const float*)d_in[0];
  const float* Wqkv = (const float*)d_in[2];
  const float* bqkv = (const float*)d_in[3];
  const float* Wd   = (const float*)d_in[4];
  const float* bd   = (const float*)d_in[5];
  float* out = (float*)d_out;
  char* ws = (char*)d_ws;

  const size_t OFF_HID  = 0;
  const size_t OFF_WQKV = 16777216;
  const size_t OFF_WD   = 41943040;
  const size_t OFF_COS  = 50331648;
  const size_t OFF_SIN  = 50855936;
  const size_t OFF_Q    = 51380224;
  const size_t OFF_K    = 68157440;
  const size_t OFF_V    = 84934656;
  const size_t OFF_VT   = 101711872;
  if (ws_size < 118489088) return;

  unsigned short* hidb  = (unsigned short*)(ws + OFF_HID);
  unsigned short* wqkvb = (unsigned short*)(ws + OFF_WQKV);
  unsigned short* wdb   = (unsigned short*)(ws + OFF_WD);
  float* cosT = (float*)(ws + OFF_COS);
  float* sinT = (float*)(ws + OFF_SIN);
  unsigned short* Qsb = (unsigned short*)(ws + OFF_Q);
  unsigned short* Ksb = (unsigned short*)(ws + OFF_K);
  unsigned short* Vpb = (unsigned short*)(ws + OFF_V);
  unsigned short* Vtb = (unsigned short*)(ws + OFF_VT);
  unsigned short* ctxb = hidb;

  conv_swz<<<8192, 256, 0, stream>>>(hidden, hidb);
  conv_swz<<<12288, 256, 0, stream>>>(Wqkv, wqkvb);
  conv_swz<<<4096, 256, 0, stream>>>(Wd, wdb);
  rope_cache_k<<<512, 256, 0, stream>>>(cosT, sinT);

  gemm_qkv<<<256, 512, 0, stream>>>(hidb, wqkvb, bqkv, Qsb, Ksb, Vpb, cosT, sinT);
  transpose_v<<<1024, 256, 0, stream>>>(Vpb, Vtb);
  attn<<<512, 256, 0, stream>>>(Qsb, Ksb, Vtb, ctxb);
  gemm8p<1><<<dim3(8, 16), 512, 0, stream>>>(ctxb, wdb, bd, out);
}

// Round 5
// 254.400 us; speedup vs baseline: 1.9971x; 1.9971x over previous
//
#include <hip/hip_runtime.h>

#define SEQ   2048
#define BATCH 2
#define HID   2048
#define NHEAD 16
#define HDIM  128
#define MTOT  4096
#define KDIM  2048

typedef __attribute__((ext_vector_type(8))) short  bf16x8;
typedef __attribute__((ext_vector_type(4))) float  f32x4;
typedef __attribute__((ext_vector_type(4))) unsigned short u16x4;
typedef __attribute__((ext_vector_type(8))) unsigned short u16x8;

__device__ __forceinline__ unsigned short f2bf(float x) {
  unsigned u = __float_as_uint(x);
  u += 0x7fffu + ((u >> 16) & 1u);
  return (unsigned short)(u >> 16);
}

__device__ __forceinline__ float fexp2(float x) {
  float r;
  asm("v_exp_f32 %0, %1" : "=v"(r) : "v"(x));
  return r;
}

__device__ __forceinline__ void gl_lds16(const void* g, void* l) {
  __builtin_amdgcn_global_load_lds(
      (__attribute__((address_space(1))) void*)g,
      (__attribute__((address_space(3))) void*)l, 16, 0, 0);
}

__device__ __forceinline__ f32x4 mfma16(bf16x8 a, bf16x8 b, f32x4 c) {
  return __builtin_amdgcn_mfma_f32_16x16x32_bf16(a, b, c, 0, 0, 0);
}

// fp32 -> bf16 with K-granule swizzle (rows of length 2048):
// element (r,k) stored at r*2048 + (k ^ (((r>>1)&3)<<3))
__global__ __launch_bounds__(256, 8)
void conv_swz(const float* __restrict__ src, unsigned short* __restrict__ dst) {
  int i = blockIdx.x * 256 + threadIdx.x;
  int base = i << 2;
  int r = base >> 11, k = base & 2047;
  f32x4 v = *(const f32x4*)(src + base);
  int kp = k ^ (((r >> 1) & 3) << 3);
  u16x4 o;
  o[0] = f2bf(v[0]); o[1] = f2bf(v[1]); o[2] = f2bf(v[2]); o[3] = f2bf(v[3]);
  *(u16x4*)(dst + (size_t)r * 2048 + kp) = o;
}

__global__ __launch_bounds__(256, 8)
void rope_cache_k(float* __restrict__ cosT, float* __restrict__ sinT) {
  int idx = blockIdx.x * 256 + threadIdx.x;   // 2048*64
  int s = idx >> 6, i = idx & 63;
  float inv = powf(1e-4f, (float)i * (1.0f / 64.0f));
  float a = (float)s * inv;
  cosT[idx] = cosf(a);
  sinT[idx] = sinf(a);
}

// ---------------------------------------------------------------------------
// QKV GEMM: 128x384 tile (N-tile = one head's q|k|v triple), BK=32,
// grid 32x16 = 512 blocks = EXACTLY 2 full dispatch rounds at 1 block/CU.
// 8 waves = 2M x 4N; wave rows [wr*64,+64); col-frags nf = wc + 4*nl
// (nl=0..5) -> RoPE pairs (nl even, nl odd) stay in-wave.
// acc[4][6] = 96 VGPR/thread (spill-free; r4's 256x384 spilled ~1.2 GB).
// LDS ring-3: A[buf][128][32] (8K) @0, B[buf][384][32] (24K) @24576 = 96 KiB.
// Loads/tile = 4 (A:1 + B:3); vmcnt(4) once per tile; 2 phases x 12 MFMA.
// ---------------------------------------------------------------------------
__global__ __launch_bounds__(512, 2)
void gemm_qkv(const unsigned short* __restrict__ A,
              const unsigned short* __restrict__ Bt,
              const float* __restrict__ bias,
              unsigned short* __restrict__ Qs,
              unsigned short* __restrict__ Ks,
              unsigned short* __restrict__ Vp,
              const float* __restrict__ cosT,
              const float* __restrict__ sinT)
{
  __shared__ alignas(16) char lds[98304];   // 96 KiB
  const int tid = threadIdx.x;
  const int wid = tid >> 6, lane = tid & 63, g = lane >> 4, c = lane & 15;
  const int wr = wid >> 2, wc = wid & 3;

  // XCD swizzle (512 % 8 == 0, bijective): XCD x -> mblk [x*4,x*4+4), all nblk
  const int bid = blockIdx.x;
  const int swz = (bid & 7) * 64 + (bid >> 3);
  const int nblk = swz & 15, mblk = swz >> 4;
  const int m0 = mblk << 7;
  const int n0 = nblk * 384;
  const int nh = nblk;

  char* ldsb = (char*)lds;
  const int slotg = (g ^ ((c >> 1) & 3)) << 4;
  const char* ldsAr = ldsb + (wr * 64 + c) * 64 + slotg;
  const char* ldsBr = ldsb + 24576 + (wc * 16 + c) * 64 + slotg;

  const char* gA = (const char*)A  + (size_t)(m0 + (tid >> 2)) * 4096 + (tid & 3) * 16;
  const char* gB = (const char*)Bt + (size_t)(n0 + (tid >> 2)) * 4096 + (tid & 3) * 16;
  char* lA = ldsb + tid * 16;
  char* lB = ldsb + 24576 + tid * 16;

#define STG_A(T, BUF) gl_lds16(gA + (T) * 64, lA + (BUF) * 8192)
#define STG_B(T, BUF) do { const char* _g = gB + (T) * 64; char* _l = lB + (BUF) * 24576; \
    gl_lds16(_g, _l); gl_lds16(_g + 524288, _l + 8192); gl_lds16(_g + 1048576, _l + 16384); } while (0)

  f32x4 acc[4][6];
#pragma unroll
  for (int i = 0; i < 4; ++i)
#pragma unroll
    for (int j = 0; j < 6; ++j) {
      acc[i][j][0] = 0.f; acc[i][j][1] = 0.f; acc[i][j][2] = 0.f; acc[i][j][3] = 0.f;
    }

  bf16x8 a[4], b0[3], b1[3];
  const int NT = KDIM / 32;   // 64

#define PH0(BUF, STAGE) do {                                                \
    _Pragma("unroll")                                                       \
    for (int mf = 0; mf < 4; ++mf)                                          \
      a[mf] = *(const bf16x8*)(ldsAr + (BUF) * 8192 + mf * 1024);           \
    _Pragma("unroll")                                                       \
    for (int nl = 0; nl < 3; ++nl)                                          \
      b0[nl] = *(const bf16x8*)(ldsBr + (BUF) * 24576 + nl * 4096);         \
    STAGE;                                                                  \
    __builtin_amdgcn_s_barrier();                                           \
    asm volatile("s_waitcnt lgkmcnt(0)" ::: "memory");                      \
    __builtin_amdgcn_s_setprio(1);                                          \
    _Pragma("unroll")                                                       \
    for (int mf = 0; mf < 4; ++mf)                                          \
      _Pragma("unroll")                                                     \
      for (int nl = 0; nl < 3; ++nl)                                        \
        acc[mf][nl] = mfma16(a[mf], b0[nl], acc[mf][nl]);                   \
    __builtin_amdgcn_s_setprio(0);                                          \
    __builtin_amdgcn_s_barrier();                                           \
  } while (0)

#define PH1(BUF, STAGE, VMW) do {                                           \
    _Pragma("unroll")                                                       \
    for (int nl = 0; nl < 3; ++nl)                                          \
      b1[nl] = *(const bf16x8*)(ldsBr + (BUF) * 24576 + (nl + 3) * 4096);   \
    STAGE;                                                                  \
    __builtin_amdgcn_s_barrier();                                           \
    asm volatile("s_waitcnt lgkmcnt(0)" ::: "memory");                      \
    __builtin_amdgcn_s_setprio(1);                                          \
    _Pragma("unroll")                                                       \
    for (int mf = 0; mf < 4; ++mf)                                          \
      _Pragma("unroll")                                                     \
      for (int nl = 0; nl < 3; ++nl)                                        \
        acc[mf][nl + 3] = mfma16(a[mf], b1[nl], acc[mf][nl + 3]);           \
    __builtin_amdgcn_s_setprio(0);                                          \
    VMW;                                                                    \
    __builtin_amdgcn_s_barrier();                                           \
  } while (0)

#define TILE(T, BUF, BUF2) do {                                             \
    PH0(BUF, { if ((T) + 2 < NT) STG_A((T) + 2, BUF2); });                  \
    PH1(BUF, { if ((T) + 2 < NT) STG_B((T) + 2, BUF2); },                   \
       { if ((T) + 2 < NT) { asm volatile("s_waitcnt vmcnt(4)" ::: "memory"); } \
         else              { asm volatile("s_waitcnt vmcnt(0)" ::: "memory"); } }); \
  } while (0)

  // Prologue: stage tiles 0,1; drain tile0's 4 loads, keep tile1's in flight.
  STG_A(0, 0); STG_B(0, 0);
  STG_A(1, 1); STG_B(1, 1);
  asm volatile("s_waitcnt vmcnt(4)" ::: "memory");
  __builtin_amdgcn_s_barrier();

  for (int t = 0; t < 63; t += 3) {
    TILE(t, 0, 2);
    TILE(t + 1, 1, 0);
    TILE(t + 2, 2, 1);
  }
  TILE(63, 0, 2);

  // ---- epilogue: bias + RoPE; nl pairs (0,1)=Q, (2,3)=K, (4,5)=V ----
  const float qsc = 0.08838834764831845f * 1.4426950408889634f; // 1/sqrt(128)*log2(e)
  const int dl = wc * 16 + c;   // 0..63
#pragma unroll
  for (int ar = 0; ar < 4; ++ar) {
#pragma unroll
    for (int rr = 0; rr < 4; ++rr) {
      int m = m0 + wr * 64 + ar * 16 + g * 4 + rr;
      int s = m >> 1, bb = m & 1;
      size_t plane = (size_t)(bb * NHEAD + nh) * (SEQ * HDIM);
      int swb = (s & 7) << 3;
      float co = cosT[s * 64 + dl], si = sinT[s * 64 + dl];
      {
        float xl = acc[ar][0][rr] + bias[n0 + dl];
        float xr = acc[ar][1][rr] + bias[n0 + 64 + dl];
        Qs[plane + (size_t)s * HDIM + (dl ^ swb)]        = f2bf((co * xl - si * xr) * qsc);
        Qs[plane + (size_t)s * HDIM + ((dl + 64) ^ swb)] = f2bf((si * xl + co * xr) * qsc);
      }
      {
        float xl = acc[ar][2][rr] + bias[n0 + 128 + dl];
        float xr = acc[ar][3][rr] + bias[n0 + 192 + dl];
        Ks[plane + (size_t)s * HDIM + (dl ^ swb)]        = f2bf(co * xl - si * xr);
        Ks[plane + (size_t)s * HDIM + ((dl + 64) ^ swb)] = f2bf(si * xl + co * xr);
      }
      Vp[plane + (size_t)s * HDIM + dl]      = f2bf(acc[ar][4][rr] + bias[n0 + 256 + dl]);
      Vp[plane + (size_t)s * HDIM + dl + 64] = f2bf(acc[ar][5][rr] + bias[n0 + 320 + dl]);
    }
  }
#undef TILE
#undef PH0
#undef PH1
#undef STG_A
#undef STG_B
}

// ---------------------------------------------------------------------------
// Dense projection GEMM: 128x256 tile, grid 32x8 = 256 blocks = 1 full round.
// 8 waves = 2M x 4N (wave = 64x64). acc[4][4] = 64 VGPR. LDS ring-3:
// A 8K @0, B 16K @24576 -> 72 KiB. Loads/tile = 3; vmcnt(3); 1 phase x 16 MFMA.
// ---------------------------------------------------------------------------
__global__ __launch_bounds__(512, 2)
void gemm_out(const unsigned short* __restrict__ A,
              const unsigned short* __restrict__ Bt,
              const float* __restrict__ bias,
              float* __restrict__ Cout)
{
  __shared__ alignas(16) char lds[73728];   // 72 KiB
  const int tid = threadIdx.x;
  const int wid = tid >> 6, lane = tid & 63, g = lane >> 4, c = lane & 15;
  const int wr = wid >> 2, wc = wid & 3;

  const int bid = blockIdx.x;
  const int swz = (bid & 7) * 32 + (bid >> 3);
  const int nblk = swz >> 5, mblk = swz & 31;
  const int m0 = mblk << 7, n0 = nblk << 8;

  char* ldsb = (char*)lds;
  const int slotg = (g ^ ((c >> 1) & 3)) << 4;
  const char* ldsAr = ldsb + (wr * 64 + c) * 64 + slotg;
  const char* ldsBr = ldsb + 24576 + (wc * 64 + c) * 64 + slotg;

  const char* gA = (const char*)A  + (size_t)(m0 + (tid >> 2)) * 4096 + (tid & 3) * 16;
  const char* gB = (const char*)Bt + (size_t)(n0 + (tid >> 2)) * 4096 + (tid & 3) * 16;
  char* lA = ldsb + tid * 16;
  char* lB = ldsb + 24576 + tid * 16;

#define STG_A(T, BUF) gl_lds16(gA + (T) * 64, lA + (BUF) * 8192)
#define STG_B(T, BUF) do { const char* _g = gB + (T) * 64; char* _l = lB + (BUF) * 16384; \
    gl_lds16(_g, _l); gl_lds16(_g + 524288, _l + 8192); } while (0)

  f32x4 acc[4][4];
#pragma unroll
  for (int i = 0; i < 4; ++i)
#pragma unroll
    for (int j = 0; j < 4; ++j) {
      acc[i][j][0] = 0.f; acc[i][j][1] = 0.f; acc[i][j][2] = 0.f; acc[i][j][3] = 0.f;
    }

  bf16x8 a[4], b[4];
  const int NT = KDIM / 32;   // 64

#define TILE(T, BUF, BUF2) do {                                             \
    _Pragma("unroll")                                                       \
    for (int mf = 0; mf < 4; ++mf)                                          \
      a[mf] = *(const bf16x8*)(ldsAr + (BUF) * 8192 + mf * 1024);           \
    _Pragma("unroll")                                                       \
    for (int nl = 0; nl < 4; ++nl)                                          \
      b[nl] = *(const bf16x8*)(ldsBr + (BUF) * 16384 + nl * 1024);          \
    if ((T) + 2 < NT) { STG_A((T) + 2, BUF2); STG_B((T) + 2, BUF2); }       \
    __builtin_amdgcn_s_barrier();                                           \
    asm volatile("s_waitcnt lgkmcnt(0)" ::: "memory");                      \
    __builtin_amdgcn_s_setprio(1);                                          \
    _Pragma("unroll")                                                       \
    for (int mf = 0; mf < 4; ++mf)                                          \
      _Pragma("unroll")                                                     \
      for (int nl = 0; nl < 4; ++nl)                                        \
        acc[mf][nl] = mfma16(a[mf], b[nl], acc[mf][nl]);                    \
    __builtin_amdgcn_s_setprio(0);                                          \
    if ((T) + 2 < NT) { asm volatile("s_waitcnt vmcnt(3)" ::: "memory"); }  \
    else              { asm volatile("s_waitcnt vmcnt(0)" ::: "memory"); }  \
    __builtin_amdgcn_s_barrier();                                           \
  } while (0)

  STG_A(0, 0); STG_B(0, 0);
  STG_A(1, 1); STG_B(1, 1);
  asm volatile("s_waitcnt vmcnt(3)" ::: "memory");
  __builtin_amdgcn_s_barrier();

  for (int t = 0; t < 63; t += 3) {
    TILE(t, 0, 2);
    TILE(t + 1, 1, 0);
    TILE(t + 2, 2, 1);
  }
  TILE(63, 0, 2);

#pragma unroll
  for (int mf = 0; mf < 4; ++mf)
#pragma unroll
    for (int rr = 0; rr < 4; ++rr) {
      int m = m0 + wr * 64 + mf * 16 + g * 4 + rr;
#pragma unroll
      for (int nl = 0; nl < 4; ++nl) {
        int n = n0 + wc * 64 + nl * 16 + c;
        Cout[(size_t)m * HID + n] = acc[mf][nl][rr] + bias[n];
      }
    }
#undef TILE
#undef STG_A
#undef STG_B
}

// V [plane][t][d] -> Vt [plane][d][t], t-granule swizzled: (t ^ ((d&7)<<3))
__global__ __launch_bounds__(256, 4)
void transpose_v(const unsigned short* __restrict__ Vp, unsigned short* __restrict__ Vt) {
  __shared__ alignas(16) unsigned short T[64 * 136];
  const int plane = blockIdx.x >> 5;
  const int t0 = (blockIdx.x & 31) << 6;
  const size_t pbase = (size_t)plane * (SEQ * HDIM);
  const int tid = threadIdx.x;
  {
    int t = tid >> 2, d0 = (tid & 3) << 5;
    const unsigned short* src = Vp + pbase + (size_t)(t0 + t) * HDIM + d0;
#pragma unroll
    for (int j = 0; j < 4; ++j) {
      u16x8 v = *(const u16x8*)(src + j * 8);
      *(u16x8*)(&T[t * 136 + d0 + j * 8]) = v;
    }
  }
  __syncthreads();
  {
    int d = tid >> 1, half = tid & 1;
    unsigned short* dstp = Vt + pbase + (size_t)d * SEQ;
    int swb = (d & 7) << 3;
#pragma unroll
    for (int gg = 0; gg < 4; ++gg) {
      u16x8 v;
#pragma unroll
      for (int e = 0; e < 8; ++e)
        v[e] = T[(half * 32 + gg * 8 + e) * 136 + d];
      int tloc = half * 32 + gg * 8;
      *(u16x8*)(dstp + ((t0 + tloc) ^ swb)) = v;
    }
  }
}

// ---------------------------------------------------------------------------
// Flash attention (unchanged from round 3)
// ---------------------------------------------------------------------------
__global__ __launch_bounds__(256, 2)
void attn(const unsigned short* __restrict__ Qs,
          const unsigned short* __restrict__ Ks,
          const unsigned short* __restrict__ Vt,
          unsigned short* __restrict__ ctx)
{
  __shared__ alignas(16) unsigned short Klds[2][64 * 128];
  __shared__ alignas(16) unsigned short Vlds[128 * 64];
  __shared__ alignas(16) unsigned short Plds[128 * 72];
  const int tid = threadIdx.x;
  const int w = tid >> 6, lane = tid & 63, g = lane >> 4, c = lane & 15;
  const int bid = blockIdx.x;
  const int head = bid & 31;
  const int qb = (bid < 256) ? (15 - (bid >> 5)) : ((bid >> 5) - 8);
  const int q0 = qb << 7;
  const size_t plane = (size_t)head * (SEQ * HDIM);
  const unsigned short* Qp = Qs + plane;
  const unsigned short* Kp = Ks + plane;
  const unsigned short* Vp = Vt + plane;

  bf16x8 qf[2][4];
#pragma unroll
  for (int q2 = 0; q2 < 2; ++q2) {
    int s = q0 + w * 32 + q2 * 16 + c;
    int swb = (s & 7) << 3;
#pragma unroll
    for (int kk = 0; kk < 4; ++kk) {
      int d0 = kk * 32 + g * 8;
      qf[q2][kk] = *(const bf16x8*)(Qp + (size_t)s * HDIM + (d0 ^ swb));
    }
  }

  f32x4 accO[2][8];
#pragma unroll
  for (int i = 0; i < 2; ++i)
#pragma unroll
    for (int j = 0; j < 8; ++j) {
      accO[i][j][0] = 0.f; accO[i][j][1] = 0.f; accO[i][j][2] = 0.f; accO[i][j][3] = 0.f;
    }
  float mrun[2] = { -1e30f, -1e30f };
  float lrun[2] = { 0.f, 0.f };

  const char* KgBase = (const char*)Kp + (tid >> 4) * 256 + (tid & 15) * 16;
  const char* VgBase = (const char*)Vp + (size_t)(tid >> 3) * 4096 + (tid & 7) * 16;
  char* VldsW = (char*)Vlds + w * 1024;

  const int ntiles = (q0 >> 6) + 2;
  const int qminw = q0 + w * 32;
  const int qmaxw = qminw + 31;

#pragma unroll
  for (int i = 0; i < 4; ++i)
    gl_lds16(KgBase, (char*)Klds[0] + w * 1024 + i * 4096), KgBase += 4096;
  KgBase -= 16384;

  for (int kt = 0; kt < ntiles; ++kt) {
    const int t0 = kt << 6;
    const bool havenext = (kt + 1 < ntiles);

#pragma unroll
    for (int i = 0; i < 4; ++i)
      gl_lds16(VgBase + t0 * 2 + (size_t)i * 131072, VldsW + i * 4096);
    if (havenext) {
      char* kdst = (char*)Klds[(kt + 1) & 1] + w * 1024;
#pragma unroll
      for (int i = 0; i < 4; ++i)
        gl_lds16(KgBase + (size_t)(t0 + 64) * 256 + i * 4096, kdst + i * 4096);
    }
    if (havenext) asm volatile("s_waitcnt vmcnt(8)" ::: "memory");
    else          asm volatile("s_waitcnt vmcnt(4)" ::: "memory");
    __builtin_amdgcn_s_barrier();

    if (t0 <= qmaxw) {
      const char* Kb = (const char*)Klds[kt & 1];
      f32x4 sacc[4][2];
#pragma unroll
      for (int i = 0; i < 4; ++i)
#pragma unroll
        for (int j = 0; j < 2; ++j) {
          sacc[i][j][0] = 0.f; sacc[i][j][1] = 0.f; sacc[i][j][2] = 0.f; sacc[i][j][3] = 0.f;
        }
      __builtin_amdgcn_s_setprio(1);
#pragma unroll
      for (int kk = 0; kk < 4; ++kk) {
        bf16x8 kf[4];
#pragma unroll
        for (int ta = 0; ta < 4; ++ta) {
          int t = ta * 16 + c;
          int d0 = kk * 32 + g * 8;
          kf[ta] = *(const bf16x8*)(Kb + t * 256 + ((d0 ^ ((t & 7) << 3)) << 1));
        }
#pragma unroll
        for (int ta = 0; ta < 4; ++ta)
#pragma unroll
          for (int q2 = 0; q2 < 2; ++q2)
            sacc[ta][q2] = mfma16(kf[ta], qf[q2][kk], sacc[ta][q2]);
      }
      __builtin_amdgcn_s_setprio(0);

      if (t0 + 63 > qminw) {
#pragma unroll
        for (int ta = 0; ta < 4; ++ta)
#pragma unroll
          for (int q2 = 0; q2 < 2; ++q2)
#pragma unroll
            for (int r = 0; r < 4; ++r) {
              int t = t0 + ta * 16 + g * 4 + r;
              int q = qminw + q2 * 16 + c;
              if (t > q) sacc[ta][q2][r] = -30000.f;
            }
      }

      float corr[2];
      bool resc = false;
#pragma unroll
      for (int q2 = 0; q2 < 2; ++q2) {
        float mx = -30000.f;
#pragma unroll
        for (int ta = 0; ta < 4; ++ta)
          mx = fmaxf(mx, fmaxf(fmaxf(sacc[ta][q2][0], sacc[ta][q2][1]),
                               fmaxf(sacc[ta][q2][2], sacc[ta][q2][3])));
        mx = fmaxf(mx, __shfl_xor(mx, 16));
        mx = fmaxf(mx, __shfl_xor(mx, 32));
        bool rs = mx > mrun[q2] + 8.0f;
        resc |= rs;
        float mnew = rs ? mx : mrun[q2];
        corr[q2] = fexp2(mrun[q2] - mnew);
        mrun[q2] = mnew;
        float ls = 0.f;
#pragma unroll
        for (int ta = 0; ta < 4; ++ta)
#pragma unroll
          for (int r = 0; r < 4; ++r) {
            float e = fexp2(sacc[ta][q2][r] - mnew);
            sacc[ta][q2][r] = e;
            ls += e;
          }
        ls += __shfl_xor(ls, 16);
        ls += __shfl_xor(ls, 32);
        lrun[q2] = lrun[q2] * corr[q2] + ls;
      }

      if (__any(resc)) {
#pragma unroll
        for (int q2 = 0; q2 < 2; ++q2)
#pragma unroll
          for (int r = 0; r < 4; ++r) {
            float cD = __shfl(corr[q2], (lane & 48) | (((lane >> 4) << 2) + r));
#pragma unroll
            for (int fn = 0; fn < 8; ++fn) accO[q2][fn][r] *= cD;
          }
      }

#pragma unroll
      for (int q2 = 0; q2 < 2; ++q2) {
        int prow = w * 32 + q2 * 16 + c;
#pragma unroll
        for (int ta = 0; ta < 4; ++ta) {
          u16x4 pk;
          pk[0] = f2bf(sacc[ta][q2][0]); pk[1] = f2bf(sacc[ta][q2][1]);
          pk[2] = f2bf(sacc[ta][q2][2]); pk[3] = f2bf(sacc[ta][q2][3]);
          *(u16x4*)(&Plds[prow * 72 + ta * 16 + g * 4]) = pk;
        }
      }
    }

    if (havenext) asm volatile("s_waitcnt vmcnt(4)" ::: "memory");
    else          asm volatile("s_waitcnt vmcnt(0)" ::: "memory");
    __builtin_amdgcn_s_barrier();

    if (t0 <= qmaxw) {
      __builtin_amdgcn_s_setprio(1);
#pragma unroll
      for (int kk = 0; kk < 2; ++kk) {
        bf16x8 pa[2];
#pragma unroll
        for (int q2 = 0; q2 < 2; ++q2)
          pa[q2] = *(const bf16x8*)((const char*)Plds + (w * 32 + q2 * 16 + c) * 144 + (kk * 32 + g * 8) * 2);
#pragma unroll
        for (int fn = 0; fn < 8; ++fn) {
          int d = fn * 16 + c;
          int tt = kk * 32 + g * 8;
          bf16x8 vb = *(const bf16x8*)((const char*)Vlds + d * 128 + ((tt ^ ((d & 7) << 3)) << 1));
#pragma unroll
          for (int q2 = 0; q2 < 2; ++q2)
            accO[q2][fn] = mfma16(pa[q2], vb, accO[q2][fn]);
        }
      }
      __builtin_amdgcn_s_setprio(0);
    }
    __builtin_amdgcn_s_barrier();
  }

  const int b = head >> 4, nh = head & 15;
  float linv[2] = { 1.0f / lrun[0], 1.0f / lrun[1] };
#pragma unroll
  for (int q2 = 0; q2 < 2; ++q2)
#pragma unroll
    for (int r = 0; r < 4; ++r) {
      float inv = __shfl(linv[q2], (lane & 48) | (((lane >> 4) << 2) + r));
      int q = q0 + w * 32 + q2 * 16 + g * 4 + r;
      int m = q * 2 + b;
      int swb = ((m >> 1) & 3) << 3;
#pragma unroll
      for (int fn = 0; fn < 8; ++fn) {
        int h = nh * 128 + fn * 16 + c;
        ctx[(size_t)m * HID + (h ^ swb)] = f2bf(accO[q2][fn][r] * inv);
      }
    }
}

extern "C" void kernel_launch(void* const* d_in, const int* in_sizes, int n_in,
                              void* d_out, int out_size, void* d_ws, size_t ws_size,
                              hipStream_t stream) {
  const float* hidden = (const float*)d_in[0];
  const float* Wqkv = (const float*)d_in[2];
  const float* bqkv = (const float*)d_in[3];
  const float* Wd   = (const float*)d_in[4];
  const float* bd   = (const float*)d_in[5];
  float* out = (float*)d_out;
  char* ws = (char*)d_ws;

  const size_t OFF_HID  = 0;
  const size_t OFF_WQKV = 16777216;
  const size_t OFF_WD   = 41943040;
  const size_t OFF_COS  = 50331648;
  const size_t OFF_SIN  = 50855936;
  const size_t OFF_Q    = 51380224;
  const size_t OFF_K    = 68157440;
  const size_t OFF_V    = 84934656;
  const size_t OFF_VT   = 101711872;
  if (ws_size < 118489088) return;

  unsigned short* hidb  = (unsigned short*)(ws + OFF_HID);
  unsigned short* wqkvb = (unsigned short*)(ws + OFF_WQKV);
  unsigned short* wdb   = (unsigned short*)(ws + OFF_WD);
  float* cosT = (float*)(ws + OFF_COS);
  float* sinT = (float*)(ws + OFF_SIN);
  unsigned short* Qsb = (unsigned short*)(ws + OFF_Q);
  unsigned short* Ksb = (unsigned short*)(ws + OFF_K);
  unsigned short* Vpb = (unsigned short*)(ws + OFF_V);
  unsigned short* Vtb = (unsigned short*)(ws + OFF_VT);
  unsigned short* ctxb = hidb;

  conv_swz<<<8192, 256, 0, stream>>>(hidden, hidb);
  conv_swz<<<12288, 256, 0, stream>>>(Wqkv, wqkvb);
  conv_swz<<<4096, 256, 0, stream>>>(Wd, wdb);
  rope_cache_k<<<512, 256, 0, stream>>>(cosT, sinT);

  gemm_qkv<<<512, 512, 0, stream>>>(hidb, wqkvb, bqkv, Qsb, Ksb, Vpb, cosT, sinT);
  transpose_v<<<1024, 256, 0, stream>>>(Vpb, Vtb);
  attn<<<512, 256, 0, stream>>>(Qsb, Ksb, Vtb, ctxb);
  gemm_out<<<256, 512, 0, stream>>>(ctxb, wdb, bd, out);
}

// Round 6
// 249.425 us; speedup vs baseline: 2.0369x; 1.0199x over previous
//
#include <hip/hip_runtime.h>

#define SEQ   2048
#define BATCH 2
#define HID   2048
#define NHEAD 16
#define HDIM  128
#define MTOT  4096
#define KDIM  2048

typedef __attribute__((ext_vector_type(8))) short  bf16x8;
typedef __attribute__((ext_vector_type(4))) float  f32x4;
typedef __attribute__((ext_vector_type(4))) unsigned short u16x4;
typedef __attribute__((ext_vector_type(8))) unsigned short u16x8;

__device__ __forceinline__ unsigned short f2bf(float x) {
  unsigned u = __float_as_uint(x);
  u += 0x7fffu + ((u >> 16) & 1u);
  return (unsigned short)(u >> 16);
}

__device__ __forceinline__ float fexp2(float x) {
  float r;
  asm("v_exp_f32 %0, %1" : "=v"(r) : "v"(x));
  return r;
}

__device__ __forceinline__ void gl_lds16(const void* g, void* l) {
  __builtin_amdgcn_global_load_lds(
      (__attribute__((address_space(1))) void*)g,
      (__attribute__((address_space(3))) void*)l, 16, 0, 0);
}

__device__ __forceinline__ f32x4 mfma16(bf16x8 a, bf16x8 b, f32x4 c) {
  return __builtin_amdgcn_mfma_f32_16x16x32_bf16(a, b, c, 0, 0, 0);
}

// ---------------------------------------------------------------------------
// Fused prep: fp32->bf16 K-granule-swizzled conversions (hidden, Wqkv, Wd)
// + RoPE cos/sin table. One launch instead of four.
// conv: element (r,k) -> r*2048 + (k ^ (((r>>1)&3)<<3))
// ---------------------------------------------------------------------------
__global__ __launch_bounds__(256, 8)
void prep(const float* __restrict__ hidden, const float* __restrict__ Wqkv,
          const float* __restrict__ Wd,
          unsigned short* __restrict__ hidb, unsigned short* __restrict__ wqkvb,
          unsigned short* __restrict__ wdb,
          float* __restrict__ cosT, float* __restrict__ sinT) {
  int bid = blockIdx.x;
  if (bid < 24576) {
    const float* src; unsigned short* dst; int lb;
    if (bid < 8192)       { src = hidden; dst = hidb;  lb = bid; }
    else if (bid < 20480) { src = Wqkv;   dst = wqkvb; lb = bid - 8192; }
    else                  { src = Wd;     dst = wdb;   lb = bid - 20480; }
    int i = lb * 256 + threadIdx.x;
    int base = i << 2;
    int r = base >> 11, k = base & 2047;
    f32x4 v = *(const f32x4*)(src + base);
    int kp = k ^ (((r >> 1) & 3) << 3);
    u16x4 o;
    o[0] = f2bf(v[0]); o[1] = f2bf(v[1]); o[2] = f2bf(v[2]); o[3] = f2bf(v[3]);
    *(u16x4*)(dst + (size_t)r * 2048 + kp) = o;
  } else {
    int idx = (bid - 24576) * 256 + threadIdx.x;   // 2048*64
    int s = idx >> 6, i = idx & 63;
    float inv = powf(1e-4f, (float)i * (1.0f / 64.0f));
    float a = (float)s * inv;
    cosT[idx] = cosf(a);
    sinT[idx] = sinf(a);
  }
}

// ---------------------------------------------------------------------------
// QKV GEMM: 128x384 tile, BK=32, grid 512 = 2 full rounds. 8 waves = 2M x 4N.
// Ring-3 LDS (96 KiB). SINGLE barrier per K-tile: ring-3 staging target
// (cur+2)%3 is never the buffer being read, so the only hazard is
// "other waves' stage loads landed before my reads of the NEXT buffer":
// covered by per-wave vmcnt(4) + one s_barrier. No explicit lgkmcnt —
// compiler emits fine-grained per-use waits (MFMA starts earlier).
// ---------------------------------------------------------------------------
__global__ __launch_bounds__(512, 2)
void gemm_qkv(const unsigned short* __restrict__ A,
              const unsigned short* __restrict__ Bt,
              const float* __restrict__ bias,
              unsigned short* __restrict__ Qs,
              unsigned short* __restrict__ Ks,
              unsigned short* __restrict__ Vp,
              const float* __restrict__ cosT,
              const float* __restrict__ sinT)
{
  __shared__ alignas(16) char lds[98304];   // 96 KiB
  const int tid = threadIdx.x;
  const int wid = tid >> 6, lane = tid & 63, g = lane >> 4, c = lane & 15;
  const int wr = wid >> 2, wc = wid & 3;

  const int bid = blockIdx.x;
  const int swz = (bid & 7) * 64 + (bid >> 3);
  const int nblk = swz & 15, mblk = swz >> 4;
  const int m0 = mblk << 7;
  const int n0 = nblk * 384;
  const int nh = nblk;

  char* ldsb = (char*)lds;
  const int slotg = (g ^ ((c >> 1) & 3)) << 4;
  const char* ldsAr = ldsb + (wr * 64 + c) * 64 + slotg;
  const char* ldsBr = ldsb + 24576 + (wc * 16 + c) * 64 + slotg;

  const char* gA = (const char*)A  + (size_t)(m0 + (tid >> 2)) * 4096 + (tid & 3) * 16;
  const char* gB = (const char*)Bt + (size_t)(n0 + (tid >> 2)) * 4096 + (tid & 3) * 16;
  char* lA = ldsb + tid * 16;
  char* lB = ldsb + 24576 + tid * 16;

#define STG_A(T, BUF) gl_lds16(gA + (T) * 64, lA + (BUF) * 8192)
#define STG_B(T, BUF) do { const char* _g = gB + (T) * 64; char* _l = lB + (BUF) * 24576; \
    gl_lds16(_g, _l); gl_lds16(_g + 524288, _l + 8192); gl_lds16(_g + 1048576, _l + 16384); } while (0)

  f32x4 acc[4][6];
#pragma unroll
  for (int i = 0; i < 4; ++i)
#pragma unroll
    for (int j = 0; j < 6; ++j) {
      acc[i][j][0] = 0.f; acc[i][j][1] = 0.f; acc[i][j][2] = 0.f; acc[i][j][3] = 0.f;
    }

  bf16x8 a[4], b[6];
  const int NT = KDIM / 32;   // 64

#define TILE(T, BUF, BUFN) do {                                             \
    if ((T) + 2 < NT) { STG_A((T) + 2, BUFN); STG_B((T) + 2, BUFN); }       \
    _Pragma("unroll")                                                       \
    for (int mf = 0; mf < 4; ++mf)                                          \
      a[mf] = *(const bf16x8*)(ldsAr + (BUF) * 8192 + mf * 1024);           \
    _Pragma("unroll")                                                       \
    for (int nl = 0; nl < 6; ++nl)                                          \
      b[nl] = *(const bf16x8*)(ldsBr + (BUF) * 24576 + nl * 4096);          \
    __builtin_amdgcn_s_setprio(1);                                          \
    _Pragma("unroll")                                                       \
    for (int mf = 0; mf < 4; ++mf)                                          \
      _Pragma("unroll")                                                     \
      for (int nl = 0; nl < 6; ++nl)                                        \
        acc[mf][nl] = mfma16(a[mf], b[nl], acc[mf][nl]);                    \
    __builtin_amdgcn_s_setprio(0);                                          \
    if ((T) + 2 < NT) { asm volatile("s_waitcnt vmcnt(4)" ::: "memory"); }  \
    else              { asm volatile("s_waitcnt vmcnt(0)" ::: "memory"); }  \
    __builtin_amdgcn_s_barrier();                                           \
  } while (0)

  // Prologue: stage tiles 0,1; drain tile0's 4 loads, keep tile1's in flight.
  STG_A(0, 0); STG_B(0, 0);
  STG_A(1, 1); STG_B(1, 1);
  asm volatile("s_waitcnt vmcnt(4)" ::: "memory");
  __builtin_amdgcn_s_barrier();

  for (int t = 0; t < 63; t += 3) {
    TILE(t, 0, 2);
    TILE(t + 1, 1, 0);
    TILE(t + 2, 2, 1);
  }
  TILE(63, 0, 2);

  // ---- epilogue: bias + RoPE; nl pairs (0,1)=Q, (2,3)=K, (4,5)=V ----
  const float qsc = 0.08838834764831845f * 1.4426950408889634f; // 1/sqrt(128)*log2(e)
  const int dl = wc * 16 + c;   // 0..63
#pragma unroll
  for (int ar = 0; ar < 4; ++ar) {
#pragma unroll
    for (int rr = 0; rr < 4; ++rr) {
      int m = m0 + wr * 64 + ar * 16 + g * 4 + rr;
      int s = m >> 1, bb = m & 1;
      size_t plane = (size_t)(bb * NHEAD + nh) * (SEQ * HDIM);
      int swb = (s & 7) << 3;
      float co = cosT[s * 64 + dl], si = sinT[s * 64 + dl];
      {
        float xl = acc[ar][0][rr] + bias[n0 + dl];
        float xr = acc[ar][1][rr] + bias[n0 + 64 + dl];
        Qs[plane + (size_t)s * HDIM + (dl ^ swb)]        = f2bf((co * xl - si * xr) * qsc);
        Qs[plane + (size_t)s * HDIM + ((dl + 64) ^ swb)] = f2bf((si * xl + co * xr) * qsc);
      }
      {
        float xl = acc[ar][2][rr] + bias[n0 + 128 + dl];
        float xr = acc[ar][3][rr] + bias[n0 + 192 + dl];
        Ks[plane + (size_t)s * HDIM + (dl ^ swb)]        = f2bf(co * xl - si * xr);
        Ks[plane + (size_t)s * HDIM + ((dl + 64) ^ swb)] = f2bf(si * xl + co * xr);
      }
      Vp[plane + (size_t)s * HDIM + dl]      = f2bf(acc[ar][4][rr] + bias[n0 + 256 + dl]);
      Vp[plane + (size_t)s * HDIM + dl + 64] = f2bf(acc[ar][5][rr] + bias[n0 + 320 + dl]);
    }
  }
#undef TILE
#undef STG_A
#undef STG_B
}

// ---------------------------------------------------------------------------
// Dense projection GEMM: 128x256 tile, grid 256 = 1 full round.
// Same single-barrier ring-3 schedule; loads/tile = 3 -> vmcnt(3).
// ---------------------------------------------------------------------------
__global__ __launch_bounds__(512, 2)
void gemm_out(const unsigned short* __restrict__ A,
              const unsigned short* __restrict__ Bt,
              const float* __restrict__ bias,
              float* __restrict__ Cout)
{
  __shared__ alignas(16) char lds[73728];   // 72 KiB
  const int tid = threadIdx.x;
  const int wid = tid >> 6, lane = tid & 63, g = lane >> 4, c = lane & 15;
  const int wr = wid >> 2, wc = wid & 3;

  const int bid = blockIdx.x;
  const int swz = (bid & 7) * 32 + (bid >> 3);
  const int nblk = swz >> 5, mblk = swz & 31;
  const int m0 = mblk << 7, n0 = nblk << 8;

  char* ldsb = (char*)lds;
  const int slotg = (g ^ ((c >> 1) & 3)) << 4;
  const char* ldsAr = ldsb + (wr * 64 + c) * 64 + slotg;
  const char* ldsBr = ldsb + 24576 + (wc * 64 + c) * 64 + slotg;

  const char* gA = (const char*)A  + (size_t)(m0 + (tid >> 2)) * 4096 + (tid & 3) * 16;
  const char* gB = (const char*)Bt + (size_t)(n0 + (tid >> 2)) * 4096 + (tid & 3) * 16;
  char* lA = ldsb + tid * 16;
  char* lB = ldsb + 24576 + tid * 16;

#define STG_A(T, BUF) gl_lds16(gA + (T) * 64, lA + (BUF) * 8192)
#define STG_B(T, BUF) do { const char* _g = gB + (T) * 64; char* _l = lB + (BUF) * 16384; \
    gl_lds16(_g, _l); gl_lds16(_g + 524288, _l + 8192); } while (0)

  f32x4 acc[4][4];
#pragma unroll
  for (int i = 0; i < 4; ++i)
#pragma unroll
    for (int j = 0; j < 4; ++j) {
      acc[i][j][0] = 0.f; acc[i][j][1] = 0.f; acc[i][j][2] = 0.f; acc[i][j][3] = 0.f;
    }

  bf16x8 a[4], b[4];
  const int NT = KDIM / 32;   // 64

#define TILE(T, BUF, BUFN) do {                                             \
    if ((T) + 2 < NT) { STG_A((T) + 2, BUFN); STG_B((T) + 2, BUFN); }       \
    _Pragma("unroll")                                                       \
    for (int mf = 0; mf < 4; ++mf)                                          \
      a[mf] = *(const bf16x8*)(ldsAr + (BUF) * 8192 + mf * 1024);           \
    _Pragma("unroll")                                                       \
    for (int nl = 0; nl < 4; ++nl)                                          \
      b[nl] = *(const bf16x8*)(ldsBr + (BUF) * 16384 + nl * 1024);          \
    __builtin_amdgcn_s_setprio(1);                                          \
    _Pragma("unroll")                                                       \
    for (int mf = 0; mf < 4; ++mf)                                          \
      _Pragma("unroll")                                                     \
      for (int nl = 0; nl < 4; ++nl)                                        \
        acc[mf][nl] = mfma16(a[mf], b[nl], acc[mf][nl]);                    \
    __builtin_amdgcn_s_setprio(0);                                          \
    if ((T) + 2 < NT) { asm volatile("s_waitcnt vmcnt(3)" ::: "memory"); }  \
    else              { asm volatile("s_waitcnt vmcnt(0)" ::: "memory"); }  \
    __builtin_amdgcn_s_barrier();                                           \
  } while (0)

  STG_A(0, 0); STG_B(0, 0);
  STG_A(1, 1); STG_B(1, 1);
  asm volatile("s_waitcnt vmcnt(3)" ::: "memory");
  __builtin_amdgcn_s_barrier();

  for (int t = 0; t < 63; t += 3) {
    TILE(t, 0, 2);
    TILE(t + 1, 1, 0);
    TILE(t + 2, 2, 1);
  }
  TILE(63, 0, 2);

#pragma unroll
  for (int mf = 0; mf < 4; ++mf)
#pragma unroll
    for (int rr = 0; rr < 4; ++rr) {
      int m = m0 + wr * 64 + mf * 16 + g * 4 + rr;
#pragma unroll
      for (int nl = 0; nl < 4; ++nl) {
        int n = n0 + wc * 64 + nl * 16 + c;
        Cout[(size_t)m * HID + n] = acc[mf][nl][rr] + bias[n];
      }
    }
#undef TILE
#undef STG_A
#undef STG_B
}

// V [plane][t][d] -> Vt [plane][d][t], t-granule swizzled: (t ^ ((d&7)<<3))
__global__ __launch_bounds__(256, 4)
void transpose_v(const unsigned short* __restrict__ Vp, unsigned short* __restrict__ Vt) {
  __shared__ alignas(16) unsigned short T[64 * 136];
  const int plane = blockIdx.x >> 5;
  const int t0 = (blockIdx.x & 31) << 6;
  const size_t pbase = (size_t)plane * (SEQ * HDIM);
  const int tid = threadIdx.x;
  {
    int t = tid >> 2, d0 = (tid & 3) << 5;
    const unsigned short* src = Vp + pbase + (size_t)(t0 + t) * HDIM + d0;
#pragma unroll
    for (int j = 0; j < 4; ++j) {
      u16x8 v = *(const u16x8*)(src + j * 8);
      *(u16x8*)(&T[t * 136 + d0 + j * 8]) = v;
    }
  }
  __syncthreads();
  {
    int d = tid >> 1, half = tid & 1;
    unsigned short* dstp = Vt + pbase + (size_t)d * SEQ;
    int swb = (d & 7) << 3;
#pragma unroll
    for (int gg = 0; gg < 4; ++gg) {
      u16x8 v;
#pragma unroll
      for (int e = 0; e < 8; ++e)
        v[e] = T[(half * 32 + gg * 8 + e) * 136 + d];
      int tloc = half * 32 + gg * 8;
      *(u16x8*)(dstp + ((t0 + tloc) ^ swb)) = v;
    }
  }
}

// ---------------------------------------------------------------------------
// Flash attention (unchanged)
// ---------------------------------------------------------------------------
__global__ __launch_bounds__(256, 2)
void attn(const unsigned short* __restrict__ Qs,
          const unsigned short* __restrict__ Ks,
          const unsigned short* __restrict__ Vt,
          unsigned short* __restrict__ ctx)
{
  __shared__ alignas(16) unsigned short Klds[2][64 * 128];
  __shared__ alignas(16) unsigned short Vlds[128 * 64];
  __shared__ alignas(16) unsigned short Plds[128 * 72];
  const int tid = threadIdx.x;
  const int w = tid >> 6, lane = tid & 63, g = lane >> 4, c = lane & 15;
  const int bid = blockIdx.x;
  const int head = bid & 31;
  const int qb = (bid < 256) ? (15 - (bid >> 5)) : ((bid >> 5) - 8);
  const int q0 = qb << 7;
  const size_t plane = (size_t)head * (SEQ * HDIM);
  const unsigned short* Qp = Qs + plane;
  const unsigned short* Kp = Ks + plane;
  const unsigned short* Vp = Vt + plane;

  bf16x8 qf[2][4];
#pragma unroll
  for (int q2 = 0; q2 < 2; ++q2) {
    int s = q0 + w * 32 + q2 * 16 + c;
    int swb = (s & 7) << 3;
#pragma unroll
    for (int kk = 0; kk < 4; ++kk) {
      int d0 = kk * 32 + g * 8;
      qf[q2][kk] = *(const bf16x8*)(Qp + (size_t)s * HDIM + (d0 ^ swb));
    }
  }

  f32x4 accO[2][8];
#pragma unroll
  for (int i = 0; i < 2; ++i)
#pragma unroll
    for (int j = 0; j < 8; ++j) {
      accO[i][j][0] = 0.f; accO[i][j][1] = 0.f; accO[i][j][2] = 0.f; accO[i][j][3] = 0.f;
    }
  float mrun[2] = { -1e30f, -1e30f };
  float lrun[2] = { 0.f, 0.f };

  const char* KgBase = (const char*)Kp + (tid >> 4) * 256 + (tid & 15) * 16;
  const char* VgBase = (const char*)Vp + (size_t)(tid >> 3) * 4096 + (tid & 7) * 16;
  char* VldsW = (char*)Vlds + w * 1024;

  const int ntiles = (q0 >> 6) + 2;
  const int qminw = q0 + w * 32;
  const int qmaxw = qminw + 31;

#pragma unroll
  for (int i = 0; i < 4; ++i)
    gl_lds16(KgBase, (char*)Klds[0] + w * 1024 + i * 4096), KgBase += 4096;
  KgBase -= 16384;

  for (int kt = 0; kt < ntiles; ++kt) {
    const int t0 = kt << 6;
    const bool havenext = (kt + 1 < ntiles);

#pragma unroll
    for (int i = 0; i < 4; ++i)
      gl_lds16(VgBase + t0 * 2 + (size_t)i * 131072, VldsW + i * 4096);
    if (havenext) {
      char* kdst = (char*)Klds[(kt + 1) & 1] + w * 1024;
#pragma unroll
      for (int i = 0; i < 4; ++i)
        gl_lds16(KgBase + (size_t)(t0 + 64) * 256 + i * 4096, kdst + i * 4096);
    }
    if (havenext) asm volatile("s_waitcnt vmcnt(8)" ::: "memory");
    else          asm volatile("s_waitcnt vmcnt(4)" ::: "memory");
    __builtin_amdgcn_s_barrier();

    if (t0 <= qmaxw) {
      const char* Kb = (const char*)Klds[kt & 1];
      f32x4 sacc[4][2];
#pragma unroll
      for (int i = 0; i < 4; ++i)
#pragma unroll
        for (int j = 0; j < 2; ++j) {
          sacc[i][j][0] = 0.f; sacc[i][j][1] = 0.f; sacc[i][j][2] = 0.f; sacc[i][j][3] = 0.f;
        }
      __builtin_amdgcn_s_setprio(1);
#pragma unroll
      for (int kk = 0; kk < 4; ++kk) {
        bf16x8 kf[4];
#pragma unroll
        for (int ta = 0; ta < 4; ++ta) {
          int t = ta * 16 + c;
          int d0 = kk * 32 + g * 8;
          kf[ta] = *(const bf16x8*)(Kb + t * 256 + ((d0 ^ ((t & 7) << 3)) << 1));
        }
#pragma unroll
        for (int ta = 0; ta < 4; ++ta)
#pragma unroll
          for (int q2 = 0; q2 < 2; ++q2)
            sacc[ta][q2] = mfma16(kf[ta], qf[q2][kk], sacc[ta][q2]);
      }
      __builtin_amdgcn_s_setprio(0);

      if (t0 + 63 > qminw) {
#pragma unroll
        for (int ta = 0; ta < 4; ++ta)
#pragma unroll
          for (int q2 = 0; q2 < 2; ++q2)
#pragma unroll
            for (int r = 0; r < 4; ++r) {
              int t = t0 + ta * 16 + g * 4 + r;
              int q = qminw + q2 * 16 + c;
              if (t > q) sacc[ta][q2][r] = -30000.f;
            }
      }

      float corr[2];
      bool resc = false;
#pragma unroll
      for (int q2 = 0; q2 < 2; ++q2) {
        float mx = -30000.f;
#pragma unroll
        for (int ta = 0; ta < 4; ++ta)
          mx = fmaxf(mx, fmaxf(fmaxf(sacc[ta][q2][0], sacc[ta][q2][1]),
                               fmaxf(sacc[ta][q2][2], sacc[ta][q2][3])));
        mx = fmaxf(mx, __shfl_xor(mx, 16));
        mx = fmaxf(mx, __shfl_xor(mx, 32));
        bool rs = mx > mrun[q2] + 8.0f;
        resc |= rs;
        float mnew = rs ? mx : mrun[q2];
        corr[q2] = fexp2(mrun[q2] - mnew);
        mrun[q2] = mnew;
        float ls = 0.f;
#pragma unroll
        for (int ta = 0; ta < 4; ++ta)
#pragma unroll
          for (int r = 0; r < 4; ++r) {
            float e = fexp2(sacc[ta][q2][r] - mnew);
            sacc[ta][q2][r] = e;
            ls += e;
          }
        ls += __shfl_xor(ls, 16);
        ls += __shfl_xor(ls, 32);
        lrun[q2] = lrun[q2] * corr[q2] + ls;
      }

      if (__any(resc)) {
#pragma unroll
        for (int q2 = 0; q2 < 2; ++q2)
#pragma unroll
          for (int r = 0; r < 4; ++r) {
            float cD = __shfl(corr[q2], (lane & 48) | (((lane >> 4) << 2) + r));
#pragma unroll
            for (int fn = 0; fn < 8; ++fn) accO[q2][fn][r] *= cD;
          }
      }

#pragma unroll
      for (int q2 = 0; q2 < 2; ++q2) {
        int prow = w * 32 + q2 * 16 + c;
#pragma unroll
        for (int ta = 0; ta < 4; ++ta) {
          u16x4 pk;
          pk[0] = f2bf(sacc[ta][q2][0]); pk[1] = f2bf(sacc[ta][q2][1]);
          pk[2] = f2bf(sacc[ta][q2][2]); pk[3] = f2bf(sacc[ta][q2][3]);
          *(u16x4*)(&Plds[prow * 72 + ta * 16 + g * 4]) = pk;
        }
      }
    }

    if (havenext) asm volatile("s_waitcnt vmcnt(4)" ::: "memory");
    else          asm volatile("s_waitcnt vmcnt(0)" ::: "memory");
    __builtin_amdgcn_s_barrier();

    if (t0 <= qmaxw) {
      __builtin_amdgcn_s_setprio(1);
#pragma unroll
      for (int kk = 0; kk < 2; ++kk) {
        bf16x8 pa[2];
#pragma unroll
        for (int q2 = 0; q2 < 2; ++q2)
          pa[q2] = *(const bf16x8*)((const char*)Plds + (w * 32 + q2 * 16 + c) * 144 + (kk * 32 + g * 8) * 2);
#pragma unroll
        for (int fn = 0; fn < 8; ++fn) {
          int d = fn * 16 + c;
          int tt = kk * 32 + g * 8;
          bf16x8 vb = *(const bf16x8*)((const char*)Vlds + d * 128 + ((tt ^ ((d & 7) << 3)) << 1));
#pragma unroll
          for (int q2 = 0; q2 < 2; ++q2)
            accO[q2][fn] = mfma16(pa[q2], vb, accO[q2][fn]);
        }
      }
      __builtin_amdgcn_s_setprio(0);
    }
    __builtin_amdgcn_s_barrier();
  }

  const int b = head >> 4, nh = head & 15;
  float linv[2] = { 1.0f / lrun[0], 1.0f / lrun[1] };
#pragma unroll
  for (int q2 = 0; q2 < 2; ++q2)
#pragma unroll
    for (int r = 0; r < 4; ++r) {
      float inv = __shfl(linv[q2], (lane & 48) | (((lane >> 4) << 2) + r));
      int q = q0 + w * 32 + q2 * 16 + g * 4 + r;
      int m = q * 2 + b;
      int swb = ((m >> 1) & 3) << 3;
#pragma unroll
      for (int fn = 0; fn < 8; ++fn) {
        int h = nh * 128 + fn * 16 + c;
        ctx[(size_t)m * HID + (h ^ swb)] = f2bf(accO[q2][fn][r] * inv);
      }
    }
}

extern "C" void kernel_launch(void* const* d_in, const int* in_sizes, int n_in,
                              void* d_out, int out_size, void* d_ws, size_t ws_size,
                              hipStream_t stream) {
  const float* hidden = (const float*)d_in[0];
  const float* Wqkv = (const float*)d_in[2];
  const float* bqkv = (const float*)d_in[3];
  const float* Wd   = (const float*)d_in[4];
  const float* bd   = (const float*)d_in[5];
  float* out = (float*)d_out;
  char* ws = (char*)d_ws;

  const size_t OFF_HID  = 0;
  const size_t OFF_WQKV = 16777216;
  const size_t OFF_WD   = 41943040;
  const size_t OFF_COS  = 50331648;
  const size_t OFF_SIN  = 50855936;
  const size_t OFF_Q    = 51380224;
  const size_t OFF_K    = 68157440;
  const size_t OFF_V    = 84934656;
  const size_t OFF_VT   = 101711872;
  if (ws_size < 118489088) return;

  unsigned short* hidb  = (unsigned short*)(ws + OFF_HID);
  unsigned short* wqkvb = (unsigned short*)(ws + OFF_WQKV);
  unsigned short* wdb   = (unsigned short*)(ws + OFF_WD);
  float* cosT = (float*)(ws + OFF_COS);
  float* sinT = (float*)(ws + OFF_SIN);
  unsigned short* Qsb = (unsigned short*)(ws + OFF_Q);
  unsigned short* Ksb = (unsigned short*)(ws + OFF_K);
  unsigned short* Vpb = (unsigned short*)(ws + OFF_V);
  unsigned short* Vtb = (unsigned short*)(ws + OFF_VT);
  unsigned short* ctxb = hidb;

  prep<<<25088, 256, 0, stream>>>(hidden, Wqkv, Wd, hidb, wqkvb, wdb, cosT, sinT);

  gemm_qkv<<<512, 512, 0, stream>>>(hidb, wqkvb, bqkv, Qsb, Ksb, Vpb, cosT, sinT);
  transpose_v<<<1024, 256, 0, stream>>>(Vpb, Vtb);
  attn<<<512, 256, 0, stream>>>(Qsb, Ksb, Vtb, ctxb);
  gemm_out<<<256, 512, 0, stream>>>(ctxb, wdb, bd, out);
}